// Round 1
// baseline (1172.697 us; speedup 1.0000x reference)
//
#include <hip/hip_runtime.h>

constexpr int N    = 100000;
constexpr int E    = 1000000;
constexpr int FIN  = 64;
constexpr int HID  = 128;
constexpr int NCLS = 32;
constexpr int G    = 1024;
constexpr float EPS = 1e-5f;

__global__ void k_deg_init(float* deg) {
  int i = blockIdx.x * blockDim.x + threadIdx.x;
  if (i < N) deg[i] = 1.0f;
}

__global__ void k_deg_acc(const int* __restrict__ dst, float* deg) {
  int e = blockIdx.x * blockDim.x + threadIdx.x;
  if (e < E) atomicAdd(&deg[dst[e]], 1.0f);
}

__global__ void k_dinv(float* deg) {
  int i = blockIdx.x * blockDim.x + threadIdx.x;
  if (i < N) deg[i] = rsqrtf(deg[i]);
}

// agg[i] = x[i] * dinv[i]^2   (self-loop contribution, also initializes agg)
__global__ void k_selfloop(const float4* __restrict__ x4, const float* __restrict__ dinv,
                           float4* __restrict__ agg4) {
  int i = blockIdx.x * blockDim.x + threadIdx.x;  // over N*16 float4s
  if (i >= N * 16) return;
  int node = i >> 4;
  float c = dinv[node];
  c *= c;
  float4 v = x4[i];
  v.x *= c; v.y *= c; v.z *= c; v.w *= c;
  agg4[i] = v;
}

// 16 lanes per edge, float4 each: agg[dst] += x[src] * dinv[src]*dinv[dst]
__global__ void k_edge(const int* __restrict__ src, const int* __restrict__ dst,
                       const float4* __restrict__ x4, const float* __restrict__ dinv,
                       float* __restrict__ agg) {
  long long t = (long long)blockIdx.x * blockDim.x + threadIdx.x;
  int e = (int)(t >> 4);
  if (e >= E) return;
  int lane = (int)(t & 15);
  int s = src[e], d = dst[e];
  float c = dinv[s] * dinv[d];
  float4 v = x4[s * 16 + lane];
  float* p = agg + (long long)d * 64 + lane * 4;
  atomicAdd(p + 0, v.x * c);
  atomicAdd(p + 1, v.y * c);
  atomicAdd(p + 2, v.z * c);
  atomicAdd(p + 3, v.w * c);
}

// h[N,128] = agg[N,64] @ W[64,128] + b
__global__ __launch_bounds__(256) void k_gemm(const float* __restrict__ agg,
                                              const float* __restrict__ W,
                                              const float* __restrict__ b,
                                              float* __restrict__ h) {
  __shared__ float Wl[64 * 128];
  __shared__ float rowbuf[2 * 64];
  int tid = threadIdx.x;
  for (int i = tid; i < 64 * 128; i += 256) Wl[i] = W[i];
  int col = tid & 127;
  int rp  = tid >> 7;
  float bias = b[col];
  __syncthreads();
  for (int r0 = blockIdx.x * 2; r0 < N; r0 += gridDim.x * 2) {
    __syncthreads();
    if (tid < 128) {
      int rr = r0 + (tid >> 6);
      rowbuf[tid] = agg[(long long)rr * 64 + (tid & 63)];
    }
    __syncthreads();
    int r = r0 + rp;
    float acc = bias;
    const float* rb = rowbuf + rp * 64;
#pragma unroll
    for (int k = 0; k < 64; ++k) acc += rb[k] * Wl[k * 128 + col];
    h[(long long)r * 128 + col] = acc;
  }
}

__global__ __launch_bounds__(256) void k_bn1_stats(const float* __restrict__ h,
                                                   float* __restrict__ sums) {
  int tid = threadIdx.x;
  int col = tid & 127;
  int rp  = tid >> 7;
  float s = 0.f, s2 = 0.f;
  for (int r = blockIdx.x * 2 + rp; r < N; r += gridDim.x * 2) {
    float v = h[(long long)r * 128 + col];
    s += v; s2 += v * v;
  }
  __shared__ float red[256], red2[256];
  red[tid] = s; red2[tid] = s2;
  __syncthreads();
  if (tid < 128) {
    atomicAdd(&sums[col], red[tid] + red[tid + 128]);
    atomicAdd(&sums[col + 128], red2[tid] + red2[tid + 128]);
  }
}

// turn (sum, sumsq) into (scale, shift) in place
__global__ void k_bn1_final(float* sums, const float* __restrict__ w,
                            const float* __restrict__ bb) {
  int c = threadIdx.x;  // 128 threads
  float mu  = sums[c] * (1.0f / N);
  float var = sums[c + 128] * (1.0f / N) - mu * mu;
  float rs  = rsqrtf(var + EPS);
  float sc  = rs * w[c];
  sums[c]       = sc;
  sums[c + 128] = bb[c] - mu * sc;
}

// one block per graph: BN1-normalize + ReLU + mean pool (batch is sorted)
__global__ __launch_bounds__(256) void k_pool(const float* __restrict__ h,
                                              const float* __restrict__ ss,
                                              const int* __restrict__ batch,
                                              float* __restrict__ pooled) {
  int g = blockIdx.x;
  int lo = 0, hi = N;
  while (lo < hi) { int m = (lo + hi) >> 1; if (batch[m] < g) lo = m + 1; else hi = m; }
  int lo2 = lo, hi2 = N;
  while (lo2 < hi2) { int m = (lo2 + hi2) >> 1; if (batch[m] < g + 1) lo2 = m + 1; else hi2 = m; }
  int start = lo, end = lo2;
  int tid = threadIdx.x;
  int col = tid & 127, rp = tid >> 7;
  float sc = ss[col], sh = ss[col + 128];
  float s = 0.f;
  for (int r = start + rp; r < end; r += 2) {
    float v = h[(long long)r * 128 + col] * sc + sh;
    s += fmaxf(v, 0.f);
  }
  __shared__ float red[256];
  red[tid] = s;
  __syncthreads();
  if (tid < 128) {
    float cnt = fmaxf((float)(end - start), 1.0f);
    pooled[g * 128 + col] = (red[tid] + red[tid + 128]) / cnt;
  }
}

__global__ __launch_bounds__(256) void k_head(const float* __restrict__ pooled,
                                              const float* __restrict__ W,
                                              const float* __restrict__ b,
                                              float* __restrict__ outpre) {
  int idx = blockIdx.x * blockDim.x + threadIdx.x;
  if (idx >= G * NCLS) return;
  int g = idx >> 5, c = idx & 31;
  float acc = b[c];
  const float* pr = pooled + g * 128;
#pragma unroll
  for (int k = 0; k < 128; ++k) acc += pr[k] * W[k * 32 + c];
  outpre[idx] = acc;
}

__global__ __launch_bounds__(1024) void k_bn2(const float* __restrict__ outpre,
                                              const float* __restrict__ w,
                                              const float* __restrict__ b,
                                              float* __restrict__ out) {
  __shared__ float red[1024];
  __shared__ float mus[32], rss[32];
  int tid = threadIdx.x;
  int col = tid & 31, grp = tid >> 5;
  float s = 0.f;
  for (int r = grp; r < G; r += 32) s += outpre[r * 32 + col];
  red[tid] = s;
  __syncthreads();
  for (int off = 512; off >= 32; off >>= 1) {
    if (tid < off) red[tid] += red[tid + off];
    __syncthreads();
  }
  if (tid < 32) mus[col] = red[col] * (1.0f / G);
  __syncthreads();
  float mu = mus[col];
  float s2 = 0.f;
  for (int r = grp; r < G; r += 32) { float d = outpre[r * 32 + col] - mu; s2 += d * d; }
  __syncthreads();
  red[tid] = s2;
  __syncthreads();
  for (int off = 512; off >= 32; off >>= 1) {
    if (tid < off) red[tid] += red[tid + off];
    __syncthreads();
  }
  if (tid < 32) rss[col] = rsqrtf(red[col] * (1.0f / G) + EPS);
  __syncthreads();
  float rs = rss[col], wc = w[col], bc = b[col];
  for (int r = grp; r < G; r += 32)
    out[r * 32 + col] = (outpre[r * 32 + col] - mu) * rs * wc + bc;
}

extern "C" void kernel_launch(void* const* d_in, const int* in_sizes, int n_in,
                              void* d_out, int out_size, void* d_ws, size_t ws_size,
                              hipStream_t stream) {
  const float* x   = (const float*)d_in[0];
  const int* ei    = (const int*)d_in[1];
  const int* batch = (const int*)d_in[2];
  const float* Wg  = (const float*)d_in[3];
  const float* bg  = (const float*)d_in[4];
  const float* w1  = (const float*)d_in[5];
  const float* b1  = (const float*)d_in[6];
  const float* Wo  = (const float*)d_in[7];
  const float* bo  = (const float*)d_in[8];
  const float* w2  = (const float*)d_in[9];
  const float* b2  = (const float*)d_in[10];

  float* ws     = (float*)d_ws;
  float* dinv   = ws;                      // N (padded to 100352)
  float* agg    = ws + 100352;             // N*64
  float* h      = agg + (long long)N * 64; // N*128
  float* sums   = h + (long long)N * 128;  // 256
  float* pooled = sums + 256;              // G*128
  float* outpre = pooled + G * 128;        // G*32

  const int* src = ei;
  const int* dst = ei + E;

  hipMemsetAsync(sums, 0, 256 * sizeof(float), stream);
  k_deg_init<<<(N + 255) / 256, 256, 0, stream>>>(dinv);
  k_deg_acc<<<(E + 255) / 256, 256, 0, stream>>>(dst, dinv);
  k_dinv<<<(N + 255) / 256, 256, 0, stream>>>(dinv);
  k_selfloop<<<(N * 16 + 255) / 256, 256, 0, stream>>>((const float4*)x, dinv, (float4*)agg);
  k_edge<<<(E * 16 + 255) / 256, 256, 0, stream>>>(src, dst, (const float4*)x, dinv, agg);
  k_gemm<<<2048, 256, 0, stream>>>(agg, Wg, bg, h);
  k_bn1_stats<<<1024, 256, 0, stream>>>(h, sums);
  k_bn1_final<<<1, 128, 0, stream>>>(sums, w1, b1);
  k_pool<<<G, 256, 0, stream>>>(h, sums, batch, pooled);
  k_head<<<(G * NCLS + 255) / 256, 256, 0, stream>>>(pooled, Wo, bo, outpre);
  k_bn2<<<1, 1024, 0, stream>>>(outpre, w2, b2, (float*)d_out);
}

// Round 2
// 628.924 us; speedup vs baseline: 1.8646x; 1.8646x over previous
//
#include <hip/hip_runtime.h>

constexpr int N    = 100000;
constexpr int E    = 1000000;
constexpr int FIN  = 64;
constexpr int HID  = 128;
constexpr int NCLS = 32;
constexpr int G    = 1024;
constexpr float EPS = 1e-5f;

// histogram of dst -> counts (in-degree, excludes self loop)
__global__ void k_hist(const int* __restrict__ dst, int* __restrict__ counts) {
  int e = blockIdx.x * blockDim.x + threadIdx.x;
  if (e < E) atomicAdd(&counts[dst[e]], 1);
}

// dinv[i] = rsqrt(counts[i] + 1)
__global__ void k_dinv(const int* __restrict__ counts, float* __restrict__ dinv) {
  int i = blockIdx.x * blockDim.x + threadIdx.x;
  if (i < N) dinv[i] = rsqrtf((float)counts[i] + 1.0f);
}

// single-block exclusive scan: counts[N] -> offsets[N+1], cursor[N]
__global__ __launch_bounds__(1024) void k_scan(const int* __restrict__ counts,
                                               int* __restrict__ offsets,
                                               int* __restrict__ cursor) {
  __shared__ int part[1024];
  int tid = threadIdx.x;
  const int CH = (N + 1023) / 1024;  // 98
  int lo = tid * CH;
  int hi = lo + CH < N ? lo + CH : N;
  int s = 0;
  for (int i = lo; i < hi; ++i) s += counts[i];
  part[tid] = s;
  __syncthreads();
  // Hillis-Steele inclusive scan over 1024 partials
  for (int off = 1; off < 1024; off <<= 1) {
    int t = (tid >= off) ? part[tid - off] : 0;
    __syncthreads();
    part[tid] += t;
    __syncthreads();
  }
  int run = part[tid] - s;  // exclusive prefix of this chunk
  for (int i = lo; i < hi; ++i) {
    offsets[i] = run;
    cursor[i]  = run;
    run += counts[i];
  }
  if (tid == 1023) offsets[N] = run;  // == E
}

// scatter src ids into CSR order
__global__ void k_fill(const int* __restrict__ src, const int* __restrict__ dst,
                       int* __restrict__ cursor, int* __restrict__ srclist) {
  int e = blockIdx.x * blockDim.x + threadIdx.x;
  if (e < E) {
    int pos = atomicAdd(&cursor[dst[e]], 1);
    srclist[pos] = src[e];
  }
}

// one 16-lane group per node: agg[d] = dinv[d]*( x[d]*dinv[d] + sum_s x[s]*dinv[s] )
__global__ __launch_bounds__(256) void k_gather(const int* __restrict__ offsets,
                                                const int* __restrict__ srclist,
                                                const float* __restrict__ dinv,
                                                const float4* __restrict__ x4,
                                                float4* __restrict__ agg4) {
  int node = blockIdx.x * 16 + (threadIdx.x >> 4);
  int lane = threadIdx.x & 15;
  if (node >= N) return;
  int start = offsets[node], end = offsets[node + 1];
  float cd = dinv[node];
  float4 acc = x4[node * 16 + lane];
  acc.x *= cd; acc.y *= cd; acc.z *= cd; acc.w *= cd;
  for (int i = start; i < end; ++i) {
    int s = srclist[i];
    float cs = dinv[s];
    float4 v = x4[s * 16 + lane];
    acc.x += v.x * cs; acc.y += v.y * cs; acc.z += v.z * cs; acc.w += v.w * cs;
  }
  acc.x *= cd; acc.y *= cd; acc.z *= cd; acc.w *= cd;
  agg4[node * 16 + lane] = acc;
}

// h[N,128] = agg[N,64] @ W[64,128] + b
__global__ __launch_bounds__(256) void k_gemm(const float* __restrict__ agg,
                                              const float* __restrict__ W,
                                              const float* __restrict__ b,
                                              float* __restrict__ h) {
  __shared__ float Wl[64 * 128];
  __shared__ float rowbuf[2 * 64];
  int tid = threadIdx.x;
  for (int i = tid; i < 64 * 128; i += 256) Wl[i] = W[i];
  int col = tid & 127;
  int rp  = tid >> 7;
  float bias = b[col];
  __syncthreads();
  for (int r0 = blockIdx.x * 2; r0 < N; r0 += gridDim.x * 2) {
    __syncthreads();
    if (tid < 128) {
      int rr = r0 + (tid >> 6);
      rowbuf[tid] = agg[(long long)rr * 64 + (tid & 63)];
    }
    __syncthreads();
    int r = r0 + rp;
    float acc = bias;
    const float* rb = rowbuf + rp * 64;
#pragma unroll
    for (int k = 0; k < 64; ++k) acc += rb[k] * Wl[k * 128 + col];
    h[(long long)r * 128 + col] = acc;
  }
}

__global__ __launch_bounds__(256) void k_bn1_stats(const float* __restrict__ h,
                                                   float* __restrict__ sums) {
  int tid = threadIdx.x;
  int col = tid & 127;
  int rp  = tid >> 7;
  float s = 0.f, s2 = 0.f;
  for (int r = blockIdx.x * 2 + rp; r < N; r += gridDim.x * 2) {
    float v = h[(long long)r * 128 + col];
    s += v; s2 += v * v;
  }
  __shared__ float red[256], red2[256];
  red[tid] = s; red2[tid] = s2;
  __syncthreads();
  if (tid < 128) {
    atomicAdd(&sums[col], red[tid] + red[tid + 128]);
    atomicAdd(&sums[col + 128], red2[tid] + red2[tid + 128]);
  }
}

// turn (sum, sumsq) into (scale, shift) in place
__global__ void k_bn1_final(float* sums, const float* __restrict__ w,
                            const float* __restrict__ bb) {
  int c = threadIdx.x;  // 128 threads
  float mu  = sums[c] * (1.0f / N);
  float var = sums[c + 128] * (1.0f / N) - mu * mu;
  float rs  = rsqrtf(var + EPS);
  float sc  = rs * w[c];
  sums[c]       = sc;
  sums[c + 128] = bb[c] - mu * sc;
}

// one block per graph: BN1-normalize + ReLU + mean pool (batch is sorted)
__global__ __launch_bounds__(256) void k_pool(const float* __restrict__ h,
                                              const float* __restrict__ ss,
                                              const int* __restrict__ batch,
                                              float* __restrict__ pooled) {
  int g = blockIdx.x;
  int lo = 0, hi = N;
  while (lo < hi) { int m = (lo + hi) >> 1; if (batch[m] < g) lo = m + 1; else hi = m; }
  int lo2 = lo, hi2 = N;
  while (lo2 < hi2) { int m = (lo2 + hi2) >> 1; if (batch[m] < g + 1) lo2 = m + 1; else hi2 = m; }
  int start = lo, end = lo2;
  int tid = threadIdx.x;
  int col = tid & 127, rp = tid >> 7;
  float sc = ss[col], sh = ss[col + 128];
  float s = 0.f;
  for (int r = start + rp; r < end; r += 2) {
    float v = h[(long long)r * 128 + col] * sc + sh;
    s += fmaxf(v, 0.f);
  }
  __shared__ float red[256];
  red[tid] = s;
  __syncthreads();
  if (tid < 128) {
    float cnt = fmaxf((float)(end - start), 1.0f);
    pooled[g * 128 + col] = (red[tid] + red[tid + 128]) / cnt;
  }
}

__global__ __launch_bounds__(256) void k_head(const float* __restrict__ pooled,
                                              const float* __restrict__ W,
                                              const float* __restrict__ b,
                                              float* __restrict__ outpre) {
  int idx = blockIdx.x * blockDim.x + threadIdx.x;
  if (idx >= G * NCLS) return;
  int g = idx >> 5, c = idx & 31;
  float acc = b[c];
  const float* pr = pooled + g * 128;
#pragma unroll
  for (int k = 0; k < 128; ++k) acc += pr[k] * W[k * 32 + c];
  outpre[idx] = acc;
}

__global__ __launch_bounds__(1024) void k_bn2(const float* __restrict__ outpre,
                                              const float* __restrict__ w,
                                              const float* __restrict__ b,
                                              float* __restrict__ out) {
  __shared__ float red[1024];
  __shared__ float mus[32], rss[32];
  int tid = threadIdx.x;
  int col = tid & 31, grp = tid >> 5;
  float s = 0.f;
  for (int r = grp; r < G; r += 32) s += outpre[r * 32 + col];
  red[tid] = s;
  __syncthreads();
  for (int off = 512; off >= 32; off >>= 1) {
    if (tid < off) red[tid] += red[tid + off];
    __syncthreads();
  }
  if (tid < 32) mus[col] = red[col] * (1.0f / G);
  __syncthreads();
  float mu = mus[col];
  float s2 = 0.f;
  for (int r = grp; r < G; r += 32) { float d = outpre[r * 32 + col] - mu; s2 += d * d; }
  __syncthreads();
  red[tid] = s2;
  __syncthreads();
  for (int off = 512; off >= 32; off >>= 1) {
    if (tid < off) red[tid] += red[tid + off];
    __syncthreads();
  }
  if (tid < 32) rss[col] = rsqrtf(red[col] * (1.0f / G) + EPS);
  __syncthreads();
  float rs = rss[col], wc = w[col], bc = b[col];
  for (int r = grp; r < G; r += 32)
    out[r * 32 + col] = (outpre[r * 32 + col] - mu) * rs * wc + bc;
}

extern "C" void kernel_launch(void* const* d_in, const int* in_sizes, int n_in,
                              void* d_out, int out_size, void* d_ws, size_t ws_size,
                              hipStream_t stream) {
  const float* x   = (const float*)d_in[0];
  const int* ei    = (const int*)d_in[1];
  const int* batch = (const int*)d_in[2];
  const float* Wg  = (const float*)d_in[3];
  const float* bg  = (const float*)d_in[4];
  const float* w1  = (const float*)d_in[5];
  const float* b1  = (const float*)d_in[6];
  const float* Wo  = (const float*)d_in[7];
  const float* bo  = (const float*)d_in[8];
  const float* w2  = (const float*)d_in[9];
  const float* b2  = (const float*)d_in[10];

  float* ws     = (float*)d_ws;
  float* dinv   = ws;                       // 100352
  float* agg    = ws + 100352;              // N*64 = 6.4e6
  float* h      = agg + (long long)N * 64;  // N*128 = 12.8e6
  float* sums   = h + (long long)N * 128;   // 256
  float* pooled = sums + 256;               // G*128
  float* outpre = pooled + G * 128;         // G*32
  int* counts   = (int*)(outpre + G * 32);  // 100352
  int* offsets  = counts + 100352;          // N+1 (padded)
  int* cursor   = offsets + 100416;         // 100352
  int* srclist  = cursor + 100352;          // E

  const int* src = ei;
  const int* dst = ei + E;

  hipMemsetAsync(counts, 0, 100352 * sizeof(int), stream);
  hipMemsetAsync(sums, 0, 256 * sizeof(float), stream);
  k_hist<<<(E + 255) / 256, 256, 0, stream>>>(dst, counts);
  k_dinv<<<(N + 255) / 256, 256, 0, stream>>>(counts, dinv);
  k_scan<<<1, 1024, 0, stream>>>(counts, offsets, cursor);
  k_fill<<<(E + 255) / 256, 256, 0, stream>>>(src, dst, cursor, srclist);
  k_gather<<<(N + 15) / 16, 256, 0, stream>>>(offsets, srclist, dinv,
                                              (const float4*)x, (float4*)agg);
  k_gemm<<<2048, 256, 0, stream>>>(agg, Wg, bg, h);
  k_bn1_stats<<<1024, 256, 0, stream>>>(h, sums);
  k_bn1_final<<<1, 128, 0, stream>>>(sums, w1, b1);
  k_pool<<<G, 256, 0, stream>>>(h, sums, batch, pooled);
  k_head<<<(G * NCLS + 255) / 256, 256, 0, stream>>>(pooled, Wo, bo, outpre);
  k_bn2<<<1, 1024, 0, stream>>>(outpre, w2, b2, (float*)d_out);
}

// Round 4
// 421.555 us; speedup vs baseline: 2.7818x; 1.4919x over previous
//
#include <hip/hip_runtime.h>

constexpr int N    = 100000;
constexpr int E    = 1000000;
constexpr int FIN  = 64;
constexpr int HID  = 128;
constexpr int NCLS = 32;
constexpr int G    = 1024;
constexpr float EPS = 1e-5f;

constexpr int SCAN_B = (N + 1023) / 1024;  // 98 blocks

// histogram of dst -> counts (in-degree, excludes self loop)
__global__ void k_hist(const int* __restrict__ dst, int* __restrict__ counts) {
  int e = blockIdx.x * blockDim.x + threadIdx.x;
  if (e < E) atomicAdd(&counts[dst[e]], 1);
}

// dinv[i] = rsqrt(counts[i] + 1)
__global__ void k_dinv(const int* __restrict__ counts, float* __restrict__ dinv) {
  int i = blockIdx.x * blockDim.x + threadIdx.x;
  if (i < N) dinv[i] = rsqrtf((float)counts[i] + 1.0f);
}

// phase 1: per-block sums
__global__ __launch_bounds__(1024) void k_scan1(const int* __restrict__ counts,
                                                int* __restrict__ blocksum) {
  __shared__ int red[1024];
  int tid = threadIdx.x;
  int i = blockIdx.x * 1024 + tid;
  red[tid] = (i < N) ? counts[i] : 0;
  __syncthreads();
  for (int off = 512; off > 0; off >>= 1) {
    if (tid < off) red[tid] += red[tid + off];
    __syncthreads();
  }
  if (tid == 0) blocksum[blockIdx.x] = red[0];
}

// phase 2: exclusive scan of SCAN_B block sums (single small block)
__global__ __launch_bounds__(128) void k_scan2(int* __restrict__ blocksum) {
  __shared__ int part[128];
  int tid = threadIdx.x;
  int v = (tid < SCAN_B) ? blocksum[tid] : 0;
  part[tid] = v;
  __syncthreads();
  for (int off = 1; off < 128; off <<= 1) {
    int t = (tid >= off) ? part[tid - off] : 0;
    __syncthreads();
    part[tid] += t;
    __syncthreads();
  }
  if (tid < SCAN_B) blocksum[tid] = part[tid] - v;  // exclusive
}

// phase 3: per-block scan + base -> offsets, cursor
__global__ __launch_bounds__(1024) void k_scan3(const int* __restrict__ counts,
                                                const int* __restrict__ blocksum,
                                                int* __restrict__ offsets,
                                                int* __restrict__ cursor) {
  __shared__ int part[1024];
  int tid = threadIdx.x;
  int i = blockIdx.x * 1024 + tid;
  int v = (i < N) ? counts[i] : 0;
  part[tid] = v;
  __syncthreads();
  for (int off = 1; off < 1024; off <<= 1) {
    int t = (tid >= off) ? part[tid - off] : 0;
    __syncthreads();
    part[tid] += t;
    __syncthreads();
  }
  int base = blocksum[blockIdx.x];
  int excl = base + part[tid] - v;
  if (i < N) {
    offsets[i] = excl;
    cursor[i]  = excl;
    if (i == N - 1) offsets[N] = excl + v;  // == E
  }
}

// scatter src ids into CSR order
__global__ void k_fill(const int* __restrict__ src, const int* __restrict__ dst,
                       int* __restrict__ cursor, int* __restrict__ srclist) {
  int e = blockIdx.x * blockDim.x + threadIdx.x;
  if (e < E) {
    int pos = atomicAdd(&cursor[dst[e]], 1);
    srclist[pos] = src[e];
  }
}

// one 16-lane group per node: agg[d] = dinv[d]*( x[d]*dinv[d] + sum_s x[s]*dinv[s] )
__global__ __launch_bounds__(256) void k_gather(const int* __restrict__ offsets,
                                                const int* __restrict__ srclist,
                                                const float* __restrict__ dinv,
                                                const float4* __restrict__ x4,
                                                float4* __restrict__ agg4) {
  int node = blockIdx.x * 16 + (threadIdx.x >> 4);
  int lane = threadIdx.x & 15;
  if (node >= N) return;
  int start = offsets[node], end = offsets[node + 1];
  float cd = dinv[node];
  float4 acc = x4[node * 16 + lane];
  acc.x *= cd; acc.y *= cd; acc.z *= cd; acc.w *= cd;
  for (int i = start; i < end; ++i) {
    int s = srclist[i];
    float cs = dinv[s];
    float4 v = x4[s * 16 + lane];
    acc.x += v.x * cs; acc.y += v.y * cs; acc.z += v.z * cs; acc.w += v.w * cs;
  }
  acc.x *= cd; acc.y *= cd; acc.z *= cd; acc.w *= cd;
  agg4[node * 16 + lane] = acc;
}

// h[N,128] = agg[N,64] @ W[64,128] + b
__global__ __launch_bounds__(256) void k_gemm(const float* __restrict__ agg,
                                              const float* __restrict__ W,
                                              const float* __restrict__ b,
                                              float* __restrict__ h) {
  __shared__ float Wl[64 * 128];
  __shared__ float rowbuf[2 * 64];
  int tid = threadIdx.x;
  for (int i = tid; i < 64 * 128; i += 256) Wl[i] = W[i];
  int col = tid & 127;
  int rp  = tid >> 7;
  float bias = b[col];
  __syncthreads();
  for (int r0 = blockIdx.x * 2; r0 < N; r0 += gridDim.x * 2) {
    __syncthreads();
    if (tid < 128) {
      int rr = r0 + (tid >> 6);
      rowbuf[tid] = agg[(long long)rr * 64 + (tid & 63)];
    }
    __syncthreads();
    int r = r0 + rp;
    float acc = bias;
    const float* rb = rowbuf + rp * 64;
#pragma unroll
    for (int k = 0; k < 64; ++k) acc += rb[k] * Wl[k * 128 + col];
    h[(long long)r * 128 + col] = acc;
  }
}

__global__ __launch_bounds__(256) void k_bn1_stats(const float* __restrict__ h,
                                                   float* __restrict__ sums) {
  int tid = threadIdx.x;
  int col = tid & 127;
  int rp  = tid >> 7;
  float s = 0.f, s2 = 0.f;
  for (int r = blockIdx.x * 2 + rp; r < N; r += gridDim.x * 2) {
    float v = h[(long long)r * 128 + col];
    s += v; s2 += v * v;
  }
  __shared__ float red[256], red2[256];
  red[tid] = s; red2[tid] = s2;
  __syncthreads();
  if (tid < 128) {
    atomicAdd(&sums[col], red[tid] + red[tid + 128]);
    atomicAdd(&sums[col + 128], red2[tid] + red2[tid + 128]);
  }
}

// turn (sum, sumsq) into (scale, shift) in place
__global__ void k_bn1_final(float* sums, const float* __restrict__ w,
                            const float* __restrict__ bb) {
  int c = threadIdx.x;  // 128 threads
  float mu  = sums[c] * (1.0f / N);
  float var = sums[c + 128] * (1.0f / N) - mu * mu;
  float rs  = rsqrtf(var + EPS);
  float sc  = rs * w[c];
  sums[c]       = sc;
  sums[c + 128] = bb[c] - mu * sc;
}

// one block per graph: BN1-normalize + ReLU + mean pool (batch is sorted)
__global__ __launch_bounds__(256) void k_pool(const float* __restrict__ h,
                                              const float* __restrict__ ss,
                                              const int* __restrict__ batch,
                                              float* __restrict__ pooled) {
  int g = blockIdx.x;
  int lo = 0, hi = N;
  while (lo < hi) { int m = (lo + hi) >> 1; if (batch[m] < g) lo = m + 1; else hi = m; }
  int lo2 = lo, hi2 = N;
  while (lo2 < hi2) { int m = (lo2 + hi2) >> 1; if (batch[m] < g + 1) lo2 = m + 1; else hi2 = m; }
  int start = lo, end = lo2;
  int tid = threadIdx.x;
  int col = tid & 127, rp = tid >> 7;
  float sc = ss[col], sh = ss[col + 128];
  float s = 0.f;
  for (int r = start + rp; r < end; r += 2) {
    float v = h[(long long)r * 128 + col] * sc + sh;
    s += fmaxf(v, 0.f);
  }
  __shared__ float red[256];
  red[tid] = s;
  __syncthreads();
  if (tid < 128) {
    float cnt = fmaxf((float)(end - start), 1.0f);
    pooled[g * 128 + col] = (red[tid] + red[tid + 128]) / cnt;
  }
}

__global__ __launch_bounds__(256) void k_head(const float* __restrict__ pooled,
                                              const float* __restrict__ W,
                                              const float* __restrict__ b,
                                              float* __restrict__ outpre) {
  int idx = blockIdx.x * blockDim.x + threadIdx.x;
  if (idx >= G * NCLS) return;
  int g = idx >> 5, c = idx & 31;
  float acc = b[c];
  const float* pr = pooled + g * 128;
#pragma unroll
  for (int k = 0; k < 128; ++k) acc += pr[k] * W[k * 32 + c];
  outpre[idx] = acc;
}

__global__ __launch_bounds__(1024) void k_bn2(const float* __restrict__ outpre,
                                              const float* __restrict__ w,
                                              const float* __restrict__ b,
                                              float* __restrict__ out) {
  __shared__ float red[1024];
  __shared__ float mus[32], rss[32];
  int tid = threadIdx.x;
  int col = tid & 31, grp = tid >> 5;
  float s = 0.f;
  for (int r = grp; r < G; r += 32) s += outpre[r * 32 + col];
  red[tid] = s;
  __syncthreads();
  for (int off = 512; off >= 32; off >>= 1) {
    if (tid < off) red[tid] += red[tid + off];
    __syncthreads();
  }
  if (tid < 32) mus[col] = red[col] * (1.0f / G);
  __syncthreads();
  float mu = mus[col];
  float s2 = 0.f;
  for (int r = grp; r < G; r += 32) { float d = outpre[r * 32 + col] - mu; s2 += d * d; }
  __syncthreads();
  red[tid] = s2;
  __syncthreads();
  for (int off = 512; off >= 32; off >>= 1) {
    if (tid < off) red[tid] += red[tid + off];
    __syncthreads();
  }
  if (tid < 32) rss[col] = rsqrtf(red[col] * (1.0f / G) + EPS);
  __syncthreads();
  float rs = rss[col], wc = w[col], bc = b[col];
  for (int r = grp; r < G; r += 32)
    out[r * 32 + col] = (outpre[r * 32 + col] - mu) * rs * wc + bc;
}

extern "C" void kernel_launch(void* const* d_in, const int* in_sizes, int n_in,
                              void* d_out, int out_size, void* d_ws, size_t ws_size,
                              hipStream_t stream) {
  const float* x   = (const float*)d_in[0];
  const int* ei    = (const int*)d_in[1];
  const int* batch = (const int*)d_in[2];
  const float* Wg  = (const float*)d_in[3];
  const float* bg  = (const float*)d_in[4];
  const float* w1  = (const float*)d_in[5];
  const float* b1  = (const float*)d_in[6];
  const float* Wo  = (const float*)d_in[7];
  const float* bo  = (const float*)d_in[8];
  const float* w2  = (const float*)d_in[9];
  const float* b2  = (const float*)d_in[10];

  float* ws     = (float*)d_ws;
  float* dinv   = ws;                       // 100352
  float* agg    = ws + 100352;              // N*64
  float* h      = agg + (long long)N * 64;  // N*128
  float* sums   = h + (long long)N * 128;   // 256
  float* pooled = sums + 256;               // G*128
  float* outpre = pooled + G * 128;         // G*32
  int* counts   = (int*)(outpre + G * 32);  // 100352
  int* offsets  = counts + 100352;          // N+1 (padded)
  int* cursor   = offsets + 100416;         // 100352
  int* srclist  = cursor + 100352;          // E
  int* blocksum = srclist + E;              // SCAN_B (padded 128)

  const int* src = ei;
  const int* dst = ei + E;

  hipMemsetAsync(counts, 0, 100352 * sizeof(int), stream);
  hipMemsetAsync(sums, 0, 256 * sizeof(float), stream);
  k_hist<<<(E + 255) / 256, 256, 0, stream>>>(dst, counts);
  k_dinv<<<(N + 255) / 256, 256, 0, stream>>>(counts, dinv);
  k_scan1<<<SCAN_B, 1024, 0, stream>>>(counts, blocksum);
  k_scan2<<<1, 128, 0, stream>>>(blocksum);
  k_scan3<<<SCAN_B, 1024, 0, stream>>>(counts, blocksum, offsets, cursor);
  k_fill<<<(E + 255) / 256, 256, 0, stream>>>(src, dst, cursor, srclist);
  k_gather<<<(N + 15) / 16, 256, 0, stream>>>(offsets, srclist, dinv,
                                              (const float4*)x, (float4*)agg);
  k_gemm<<<2048, 256, 0, stream>>>(agg, Wg, bg, h);
  k_bn1_stats<<<1024, 256, 0, stream>>>(h, sums);
  k_bn1_final<<<1, 128, 0, stream>>>(sums, w1, b1);
  k_pool<<<G, 256, 0, stream>>>(h, sums, batch, pooled);
  k_head<<<(G * NCLS + 255) / 256, 256, 0, stream>>>(pooled, Wo, bo, outpre);
  k_bn2<<<1, 1024, 0, stream>>>(outpre, w2, b2, (float*)d_out);
}

// Round 5
// 348.537 us; speedup vs baseline: 3.3646x; 1.2095x over previous
//
#include <hip/hip_runtime.h>

constexpr int N    = 100000;
constexpr int E    = 1000000;
constexpr int FIN  = 64;
constexpr int HID  = 128;
constexpr int NCLS = 32;
constexpr int G    = 1024;
constexpr float EPS = 1e-5f;

constexpr int SCAN_B = (N + 1023) / 1024;  // 98 blocks
constexpr int NTILE  = (N + 127) / 128;    // 782 row tiles

// histogram of dst -> counts (in-degree, excludes self loop)
__global__ void k_hist(const int* __restrict__ dst, int* __restrict__ counts) {
  int e = blockIdx.x * blockDim.x + threadIdx.x;
  if (e < E) atomicAdd(&counts[dst[e]], 1);
}

// phase 1: per-block sums
__global__ __launch_bounds__(1024) void k_scan1(const int* __restrict__ counts,
                                                int* __restrict__ blocksum) {
  __shared__ int red[1024];
  int tid = threadIdx.x;
  int i = blockIdx.x * 1024 + tid;
  red[tid] = (i < N) ? counts[i] : 0;
  __syncthreads();
  for (int off = 512; off > 0; off >>= 1) {
    if (tid < off) red[tid] += red[tid + off];
    __syncthreads();
  }
  if (tid == 0) blocksum[blockIdx.x] = red[0];
}

// phase 2: exclusive scan of SCAN_B block sums (single small block)
__global__ __launch_bounds__(128) void k_scan2(int* __restrict__ blocksum) {
  __shared__ int part[128];
  int tid = threadIdx.x;
  int v = (tid < SCAN_B) ? blocksum[tid] : 0;
  part[tid] = v;
  __syncthreads();
  for (int off = 1; off < 128; off <<= 1) {
    int t = (tid >= off) ? part[tid - off] : 0;
    __syncthreads();
    part[tid] += t;
    __syncthreads();
  }
  if (tid < SCAN_B) blocksum[tid] = part[tid] - v;  // exclusive
}

// phase 3: per-block scan + base -> offsets, cursor; also dinv = rsqrt(count+1)
__global__ __launch_bounds__(1024) void k_scan3(const int* __restrict__ counts,
                                                const int* __restrict__ blocksum,
                                                int* __restrict__ offsets,
                                                int* __restrict__ cursor,
                                                float* __restrict__ dinv) {
  __shared__ int part[1024];
  int tid = threadIdx.x;
  int i = blockIdx.x * 1024 + tid;
  int v = (i < N) ? counts[i] : 0;
  part[tid] = v;
  __syncthreads();
  for (int off = 1; off < 1024; off <<= 1) {
    int t = (tid >= off) ? part[tid - off] : 0;
    __syncthreads();
    part[tid] += t;
    __syncthreads();
  }
  int base = blocksum[blockIdx.x];
  int excl = base + part[tid] - v;
  if (i < N) {
    offsets[i] = excl;
    cursor[i]  = excl;
    dinv[i]    = rsqrtf((float)v + 1.0f);
    if (i == N - 1) offsets[N] = excl + v;  // == E
  }
}

// scatter src ids into CSR order
__global__ void k_fill(const int* __restrict__ src, const int* __restrict__ dst,
                       int* __restrict__ cursor, int* __restrict__ srclist) {
  int e = blockIdx.x * blockDim.x + threadIdx.x;
  if (e < E) {
    int pos = atomicAdd(&cursor[dst[e]], 1);
    srclist[pos] = src[e];
  }
}

// one 16-lane group per node: agg[d] = dinv[d]*( x[d]*dinv[d] + sum_s x[s]*dinv[s] )
__global__ __launch_bounds__(256) void k_gather(const int* __restrict__ offsets,
                                                const int* __restrict__ srclist,
                                                const float* __restrict__ dinv,
                                                const float4* __restrict__ x4,
                                                float4* __restrict__ agg4) {
  int node = blockIdx.x * 16 + (threadIdx.x >> 4);
  int lane = threadIdx.x & 15;
  if (node >= N) return;
  int start = offsets[node], end = offsets[node + 1];
  float cd = dinv[node];
  float4 acc = x4[node * 16 + lane];
  acc.x *= cd; acc.y *= cd; acc.z *= cd; acc.w *= cd;
  for (int i = start; i < end; ++i) {
    int s = srclist[i];
    float cs = dinv[s];
    float4 v = x4[s * 16 + lane];
    acc.x += v.x * cs; acc.y += v.y * cs; acc.z += v.z * cs; acc.w += v.w * cs;
  }
  acc.x *= cd; acc.y *= cd; acc.z *= cd; acc.w *= cd;
  agg4[node * 16 + lane] = acc;
}

// h[N,128] = agg[N,64] @ W[64,128] + b, fused BN1 partial stats per 128-row tile.
// 256 thr: rt=tid>>4 (16 row-threads x 8 rows), ct=tid&15 (16 col-threads x 8 cols).
__global__ __launch_bounds__(256) void k_gemm2(const float* __restrict__ agg,
                                               const float* __restrict__ W,
                                               const float* __restrict__ b,
                                               float* __restrict__ h,
                                               float* __restrict__ partials) {
  __shared__ float Wl[64 * 128];    // [k][col]
  __shared__ float rowT[64 * 128];  // [k][row]  (transposed agg tile)
  int tid  = threadIdx.x;
  int row0 = blockIdx.x * 128;
  // stage W (straight copy, float4)
  {
    const float4* Wg4 = (const float4*)W;
    float4* Wl4 = (float4*)Wl;
    for (int i = tid; i < 2048; i += 256) Wl4[i] = Wg4[i];
  }
  // stage agg tile transposed: thread handles row r=tid&127, k-half kh=tid>>7
  {
    int r = tid & 127, kh = tid >> 7;
    int grow = row0 + r;
#pragma unroll
    for (int i = 0; i < 8; ++i) {
      int k0 = kh * 32 + i * 4;
      float4 v;
      if (grow < N) v = *(const float4*)&agg[(long long)grow * 64 + k0];
      else          v = make_float4(0.f, 0.f, 0.f, 0.f);
      rowT[(k0 + 0) * 128 + r] = v.x;
      rowT[(k0 + 1) * 128 + r] = v.y;
      rowT[(k0 + 2) * 128 + r] = v.z;
      rowT[(k0 + 3) * 128 + r] = v.w;
    }
  }
  __syncthreads();

  int rt = tid >> 4, ct = tid & 15;
  float acc[8][8];
#pragma unroll
  for (int m = 0; m < 8; ++m)
#pragma unroll
    for (int j = 0; j < 8; ++j) acc[m][j] = 0.f;

#pragma unroll 4
  for (int k = 0; k < 64; ++k) {
    float4 w0 = *(const float4*)&Wl[k * 128 + ct * 8];
    float4 w1 = *(const float4*)&Wl[k * 128 + ct * 8 + 4];
    float4 r0 = *(const float4*)&rowT[k * 128 + rt * 8];
    float4 r1 = *(const float4*)&rowT[k * 128 + rt * 8 + 4];
    float wv[8] = {w0.x, w0.y, w0.z, w0.w, w1.x, w1.y, w1.z, w1.w};
    float rv[8] = {r0.x, r0.y, r0.z, r0.w, r1.x, r1.y, r1.z, r1.w};
#pragma unroll
    for (int m = 0; m < 8; ++m)
#pragma unroll
      for (int j = 0; j < 8; ++j) acc[m][j] += rv[m] * wv[j];
  }

  int cbase = ct * 8;
  float4 b0 = *(const float4*)&b[cbase];
  float4 b1 = *(const float4*)&b[cbase + 4];
  float bias[8] = {b0.x, b0.y, b0.z, b0.w, b1.x, b1.y, b1.z, b1.w};
  float s[8], s2[8];
#pragma unroll
  for (int j = 0; j < 8; ++j) { s[j] = 0.f; s2[j] = 0.f; }
#pragma unroll
  for (int m = 0; m < 8; ++m) {
    int grow = row0 + rt * 8 + m;
    if (grow < N) {
      float hv[8];
#pragma unroll
      for (int j = 0; j < 8; ++j) {
        hv[j] = acc[m][j] + bias[j];
        s[j] += hv[j];
        s2[j] += hv[j] * hv[j];
      }
      float* hp = &h[(long long)grow * 128 + cbase];
      *(float4*)hp       = make_float4(hv[0], hv[1], hv[2], hv[3]);
      *(float4*)(hp + 4) = make_float4(hv[4], hv[5], hv[6], hv[7]);
    }
  }
  // reduce stats over the 16 rt-threads; reuse Wl as scratch (done with LDS tiles)
  __syncthreads();
  float* red = Wl;  // 16 * 256 floats
#pragma unroll
  for (int j = 0; j < 8; ++j) {
    red[rt * 256 + cbase + j]       = s[j];
    red[rt * 256 + 128 + cbase + j] = s2[j];
  }
  __syncthreads();
  float tot = 0.f;
#pragma unroll 4
  for (int r = 0; r < 16; ++r) tot += red[r * 256 + tid];
  partials[blockIdx.x * 256 + tid] = tot;  // [0:128)=sum, [128:256)=sumsq
}

// reduce partials -> scale/shift
__global__ __launch_bounds__(256) void k_bn1_final(const float* __restrict__ partials,
                                                   const float* __restrict__ w,
                                                   const float* __restrict__ bb,
                                                   float* __restrict__ ss) {
  __shared__ float tot[256];
  int tid = threadIdx.x;
  float s = 0.f;
  for (int t = 0; t < NTILE; ++t) s += partials[t * 256 + tid];
  tot[tid] = s;
  __syncthreads();
  if (tid < 128) {
    float mu  = tot[tid] * (1.0f / N);
    float var = tot[tid + 128] * (1.0f / N) - mu * mu;
    float rs  = rsqrtf(var + EPS);
    float sc  = rs * w[tid];
    ss[tid]       = sc;
    ss[tid + 128] = bb[tid] - mu * sc;
  }
}

// one block per graph: BN1-normalize + ReLU + mean pool (batch is sorted)
__global__ __launch_bounds__(256) void k_pool(const float* __restrict__ h,
                                              const float* __restrict__ ss,
                                              const int* __restrict__ batch,
                                              float* __restrict__ pooled) {
  int g = blockIdx.x;
  int lo = 0, hi = N;
  while (lo < hi) { int m = (lo + hi) >> 1; if (batch[m] < g) lo = m + 1; else hi = m; }
  int lo2 = lo, hi2 = N;
  while (lo2 < hi2) { int m = (lo2 + hi2) >> 1; if (batch[m] < g + 1) lo2 = m + 1; else hi2 = m; }
  int start = lo, end = lo2;
  int tid = threadIdx.x;
  int col = tid & 127, rp = tid >> 7;
  float sc = ss[col], sh = ss[col + 128];
  float s = 0.f;
  for (int r = start + rp; r < end; r += 2) {
    float v = h[(long long)r * 128 + col] * sc + sh;
    s += fmaxf(v, 0.f);
  }
  __shared__ float red[256];
  red[tid] = s;
  __syncthreads();
  if (tid < 128) {
    float cnt = fmaxf((float)(end - start), 1.0f);
    pooled[g * 128 + col] = (red[tid] + red[tid + 128]) / cnt;
  }
}

__global__ __launch_bounds__(256) void k_head(const float* __restrict__ pooled,
                                              const float* __restrict__ W,
                                              const float* __restrict__ b,
                                              float* __restrict__ outpre) {
  int idx = blockIdx.x * blockDim.x + threadIdx.x;
  if (idx >= G * NCLS) return;
  int g = idx >> 5, c = idx & 31;
  float acc = b[c];
  const float* pr = pooled + g * 128;
#pragma unroll
  for (int k = 0; k < 128; ++k) acc += pr[k] * W[k * 32 + c];
  outpre[idx] = acc;
}

__global__ __launch_bounds__(1024) void k_bn2(const float* __restrict__ outpre,
                                              const float* __restrict__ w,
                                              const float* __restrict__ b,
                                              float* __restrict__ out) {
  __shared__ float red[1024];
  __shared__ float mus[32], rss[32];
  int tid = threadIdx.x;
  int col = tid & 31, grp = tid >> 5;
  float s = 0.f;
  for (int r = grp; r < G; r += 32) s += outpre[r * 32 + col];
  red[tid] = s;
  __syncthreads();
  for (int off = 512; off >= 32; off >>= 1) {
    if (tid < off) red[tid] += red[tid + off];
    __syncthreads();
  }
  if (tid < 32) mus[col] = red[col] * (1.0f / G);
  __syncthreads();
  float mu = mus[col];
  float s2 = 0.f;
  for (int r = grp; r < G; r += 32) { float d = outpre[r * 32 + col] - mu; s2 += d * d; }
  __syncthreads();
  red[tid] = s2;
  __syncthreads();
  for (int off = 512; off >= 32; off >>= 1) {
    if (tid < off) red[tid] += red[tid + off];
    __syncthreads();
  }
  if (tid < 32) rss[col] = rsqrtf(red[col] * (1.0f / G) + EPS);
  __syncthreads();
  float rs = rss[col], wc = w[col], bc = b[col];
  for (int r = grp; r < G; r += 32)
    out[r * 32 + col] = (outpre[r * 32 + col] - mu) * rs * wc + bc;
}

extern "C" void kernel_launch(void* const* d_in, const int* in_sizes, int n_in,
                              void* d_out, int out_size, void* d_ws, size_t ws_size,
                              hipStream_t stream) {
  const float* x   = (const float*)d_in[0];
  const int* ei    = (const int*)d_in[1];
  const int* batch = (const int*)d_in[2];
  const float* Wg  = (const float*)d_in[3];
  const float* bg  = (const float*)d_in[4];
  const float* w1  = (const float*)d_in[5];
  const float* b1  = (const float*)d_in[6];
  const float* Wo  = (const float*)d_in[7];
  const float* bo  = (const float*)d_in[8];
  const float* w2  = (const float*)d_in[9];
  const float* b2  = (const float*)d_in[10];

  float* ws     = (float*)d_ws;
  float* dinv   = ws;                       // 100352
  float* agg    = ws + 100352;              // N*64
  float* h      = agg + (long long)N * 64;  // N*128
  float* ss     = h + (long long)N * 128;   // 256 (BN1 scale/shift)
  float* pooled = ss + 256;                 // G*128
  float* outpre = pooled + G * 128;         // G*32
  int* counts   = (int*)(outpre + G * 32);  // 100352
  int* offsets  = counts + 100352;          // N+1 (padded)
  int* cursor   = offsets + 100416;         // 100352
  int* srclist  = cursor + 100352;          // E
  int* blocksum = srclist + E;              // SCAN_B (padded 128)
  // partials aliases srclist (dead after k_gather): NTILE*256 = 200192 floats < E
  float* partials = (float*)srclist;

  const int* src = ei;
  const int* dst = ei + E;

  hipMemsetAsync(counts, 0, 100352 * sizeof(int), stream);
  k_hist<<<(E + 255) / 256, 256, 0, stream>>>(dst, counts);
  k_scan1<<<SCAN_B, 1024, 0, stream>>>(counts, blocksum);
  k_scan2<<<1, 128, 0, stream>>>(blocksum);
  k_scan3<<<SCAN_B, 1024, 0, stream>>>(counts, blocksum, offsets, cursor, dinv);
  k_fill<<<(E + 255) / 256, 256, 0, stream>>>(src, dst, cursor, srclist);
  k_gather<<<(N + 15) / 16, 256, 0, stream>>>(offsets, srclist, dinv,
                                              (const float4*)x, (float4*)agg);
  k_gemm2<<<NTILE, 256, 0, stream>>>(agg, Wg, bg, h, partials);
  k_bn1_final<<<1, 256, 0, stream>>>(partials, w1, b1, ss);
  k_pool<<<G, 256, 0, stream>>>(h, ss, batch, pooled);
  k_head<<<(G * NCLS + 255) / 256, 256, 0, stream>>>(pooled, Wo, bo, outpre);
  k_bn2<<<1, 1024, 0, stream>>>(outpre, w2, b2, (float*)d_out);
}